// Round 1
// baseline (464.121 us; speedup 1.0000x reference)
//
#include <hip/hip_runtime.h>

#define B_    512
#define KD    20000
#define EMBD  256
#define HIDD  512
#define NEMB  200000
#define SPLITS 25
#define KSPAN  800   // 20000 / 25, = 25 k-steps of 32

typedef __attribute__((ext_vector_type(8))) short bf16x8;
typedef __attribute__((ext_vector_type(4))) float f32x4;
typedef __attribute__((ext_vector_type(8))) unsigned short u16x8;

__device__ __forceinline__ unsigned short f2bf(float f) {
  unsigned int u = __float_as_uint(f);
  return (unsigned short)((u + 0x7fffu + ((u >> 16) & 1u)) >> 16);  // RNE
}

__device__ __forceinline__ float selu_f(float x) {
  const float kScale = 1.0507009873554805f;
  const float kSA    = 1.7580993408473766f;  // scale*alpha
  return x > 0.0f ? kScale * x : kSA * (__expf(x) - 1.0f);
}

// load 8 consecutive f32 and pack to bf16x8 (16B-aligned source)
__device__ __forceinline__ bf16x8 load8f(const float* __restrict__ p) {
  float4 a = *(const float4*)p;
  float4 b = *(const float4*)(p + 4);
  bf16x8 r;
  r[0] = (short)f2bf(a.x); r[1] = (short)f2bf(a.y);
  r[2] = (short)f2bf(a.z); r[3] = (short)f2bf(a.w);
  r[4] = (short)f2bf(b.x); r[5] = (short)f2bf(b.y);
  r[6] = (short)f2bf(b.z); r[7] = (short)f2bf(b.w);
  return r;
}

// ---------------- K1: split-K gather GEMM: part[kz] += rin @ en_emb[act] ----
// grid (8,4,25), block 256 (4 waves, 2x2), tile 64x64 per block
__global__ void k1_gather_gemm(const float* __restrict__ rin,
                               const int* __restrict__ act,
                               const float* __restrict__ en_emb,
                               float* __restrict__ part) {
  const int tid = threadIdx.x;
  const int lane = tid & 63, wave = tid >> 6;
  const int wm = wave >> 1, wn = wave & 1;
  const int g = lane >> 4, r16 = lane & 15;
  const int m0 = blockIdx.x * 64 + wm * 32;
  const int n0 = blockIdx.y * 64 + wn * 32;
  const int kz = blockIdx.z;
  // active_dims may be int64 (reference casts to int64): odd words all-zero
  const int is64 = ((act[1] | act[3] | act[5] | act[7]) == 0) ? 1 : 0;

  const f32x4 z4 = {0.f, 0.f, 0.f, 0.f};
  f32x4 acc[2][2];
#pragma unroll
  for (int a = 0; a < 2; ++a)
#pragma unroll
    for (int b = 0; b < 2; ++b) acc[a][b] = z4;

  for (int s = 0; s < 25; ++s) {
    const int k = kz * KSPAN + s * 32;
    const int kb = k + g * 8;
    bf16x8 afr[2];
#pragma unroll
    for (int fm = 0; fm < 2; ++fm) {
      const int row = m0 + fm * 16 + r16;
      afr[fm] = load8f(rin + (size_t)row * KD + kb);
    }
    int idx8[8];
#pragma unroll
    for (int j = 0; j < 8; ++j)
      idx8[j] = is64 ? act[(size_t)(kb + j) * 2] : act[kb + j];
    bf16x8 bfr[2];
#pragma unroll
    for (int fn = 0; fn < 2; ++fn) {
      const int e = n0 + fn * 16 + r16;
#pragma unroll
      for (int j = 0; j < 8; ++j)
        bfr[fn][j] = (short)f2bf(en_emb[(size_t)idx8[j] * EMBD + e]);
    }
#pragma unroll
    for (int fm = 0; fm < 2; ++fm)
#pragma unroll
      for (int fn = 0; fn < 2; ++fn)
        acc[fm][fn] = __builtin_amdgcn_mfma_f32_16x16x32_bf16(afr[fm], bfr[fn], acc[fm][fn], 0, 0, 0);
  }
  float* pz = part + (size_t)kz * (B_ * EMBD);
#pragma unroll
  for (int fm = 0; fm < 2; ++fm)
#pragma unroll
    for (int fn = 0; fn < 2; ++fn) {
      const int n = n0 + fn * 16 + r16;
#pragma unroll
      for (int j = 0; j < 4; ++j) {
        const int m = m0 + fm * 16 + g * 4 + j;  // C/D: row=(l>>4)*4+reg, col=l&15
        pz[(size_t)m * EMBD + n] = acc[fm][fn][j];
      }
    }
}

// ---------------- K1b: reduce splits + bias + selu -> z1 (f32) --------------
__global__ void k1_reduce(const float* __restrict__ part,
                          const float* __restrict__ en_bias,
                          float* __restrict__ z1) {
  const int i = blockIdx.x * blockDim.x + threadIdx.x;  // 0..131071
  float s = 0.f;
#pragma unroll
  for (int p = 0; p < SPLITS; ++p) s += part[(size_t)p * (B_ * EMBD) + i];
  z1[i] = selu_f(s + en_bias[i & (EMBD - 1)]);
}

// ---------------- K2/K3: small MLP GEMM (C = A @ Bw^T), register-only -------
// block 256 (2x2 waves), tile 64x64; A [M][KDIM] lda=LDA, Bw [N][KDIM] ldb=LDB
template <int KDIM, int LDA, int LDB, bool BF16OUT>
__global__ void mlp_gemm(const float* __restrict__ A,
                         const float* __restrict__ Bw,
                         const float* __restrict__ bias,
                         float* __restrict__ outF,
                         unsigned short* __restrict__ outB,
                         int ldo) {
  const int tid = threadIdx.x;
  const int lane = tid & 63, wave = tid >> 6;
  const int wm = wave >> 1, wn = wave & 1;
  const int g = lane >> 4, r16 = lane & 15;
  const int m0 = blockIdx.x * 64 + wm * 32;
  const int n0 = blockIdx.y * 64 + wn * 32;

  const f32x4 z4 = {0.f, 0.f, 0.f, 0.f};
  f32x4 acc[2][2];
#pragma unroll
  for (int a = 0; a < 2; ++a)
#pragma unroll
    for (int b = 0; b < 2; ++b) acc[a][b] = z4;

#pragma unroll
  for (int k = 0; k < KDIM; k += 32) {
    const int kb = k + g * 8;
    bf16x8 afr[2], bfr[2];
#pragma unroll
    for (int fm = 0; fm < 2; ++fm)
      afr[fm] = load8f(A + (size_t)(m0 + fm * 16 + r16) * LDA + kb);
#pragma unroll
    for (int fn = 0; fn < 2; ++fn)
      bfr[fn] = load8f(Bw + (size_t)(n0 + fn * 16 + r16) * LDB + kb);
#pragma unroll
    for (int fm = 0; fm < 2; ++fm)
#pragma unroll
      for (int fn = 0; fn < 2; ++fn)
        acc[fm][fn] = __builtin_amdgcn_mfma_f32_16x16x32_bf16(afr[fm], bfr[fn], acc[fm][fn], 0, 0, 0);
  }
#pragma unroll
  for (int fm = 0; fm < 2; ++fm)
#pragma unroll
    for (int fn = 0; fn < 2; ++fn) {
      const int n = n0 + fn * 16 + r16;
      const float bv = bias[n];
#pragma unroll
      for (int j = 0; j < 4; ++j) {
        const int m = m0 + fm * 16 + g * 4 + j;
        const float v = selu_f(acc[fm][fn][j] + bv);
        if constexpr (BF16OUT)
          outB[(size_t)m * ldo + n] = f2bf(v);
        else
          outF[(size_t)m * ldo + n] = v;
      }
    }
}

// ---------------- K4: out = z3b @ de_emb^T + de_bias ------------------------
// block 512 (8 waves, 4Mx2N), per block: 128 n-rows staged in LDS (bf16,
// XOR-swizzled), loop 4 m-chunks of 128; A-frags read from L2-resident z3b.
__global__ void k4_decode(const unsigned short* __restrict__ z3b,  // [512][256] bf16
                          const float* __restrict__ de_emb,        // [NEMB][256]
                          const float* __restrict__ de_bias,       // [NEMB]
                          float* __restrict__ out) {               // [512][NEMB]
  __shared__ unsigned short Bs[128 * 256];  // 64 KB

  // bijective XCD-aware swizzle (nwg % 8 != 0 safe)
  const int nwg = gridDim.x;
  int bid = blockIdx.x;
  const int q = nwg >> 3, r = nwg & 7;
  const int xcd = bid & 7, sub = bid >> 3;
  const int wg = (xcd < r ? xcd * (q + 1) : r * (q + 1) + (xcd - r) * q) + sub;
  const int n0 = wg * 128;

  const int tid = threadIdx.x;
  // ---- stage de_emb tile -> Bs (bf16, swizzled) ----
  {
    const int sr = tid >> 2, sq = tid & 3;  // row 0..127, quarter 0..3
    const int nrow = n0 + sr;
#pragma unroll
    for (int i = 0; i < 8; ++i) {
      const int k0 = i * 32 + sq * 8;
      u16x8 v;
      if (nrow < NEMB) {
        const float4* p = (const float4*)(de_emb + (size_t)nrow * EMBD + k0);
        float4 x = p[0], y = p[1];
        v[0] = f2bf(x.x); v[1] = f2bf(x.y); v[2] = f2bf(x.z); v[3] = f2bf(x.w);
        v[4] = f2bf(y.x); v[5] = f2bf(y.y); v[6] = f2bf(y.z); v[7] = f2bf(y.w);
      } else {
#pragma unroll
        for (int t = 0; t < 8; ++t) v[t] = 0;
      }
      const int sidx = sr * 256 + (k0 ^ ((sr & 7) << 3));
      *(u16x8*)(&Bs[sidx]) = v;
    }
  }
  __syncthreads();

  const int lane = tid & 63, wave = tid >> 6;  // 8 waves
  const int wm = wave >> 1, wn = wave & 1;     // 4(M) x 2(N)
  const int g = lane >> 4, r16 = lane & 15;

  float bias_v[4];
#pragma unroll
  for (int fn = 0; fn < 4; ++fn) {
    const int n = n0 + wn * 64 + fn * 16 + r16;
    bias_v[fn] = (n < NEMB) ? de_bias[n] : 0.f;
  }

  const f32x4 z4 = {0.f, 0.f, 0.f, 0.f};
  for (int mc = 0; mc < 4; ++mc) {
    f32x4 acc[2][4];
#pragma unroll
    for (int a = 0; a < 2; ++a)
#pragma unroll
      for (int b = 0; b < 4; ++b) acc[a][b] = z4;

#pragma unroll
    for (int kk = 0; kk < 8; ++kk) {
      bf16x8 a[2];
#pragma unroll
      for (int fm = 0; fm < 2; ++fm) {
        const int m = mc * 128 + wm * 32 + fm * 16 + r16;
        a[fm] = *(const bf16x8*)(z3b + (size_t)m * EMBD + kk * 32 + g * 8);
      }
#pragma unroll
      for (int fn = 0; fn < 4; ++fn) {
        const int rr = wn * 64 + fn * 16 + r16;
        const int koff = (kk * 32 + g * 8) ^ ((rr & 7) << 3);
        const bf16x8 b = *(const bf16x8*)(&Bs[rr * 256 + koff]);
#pragma unroll
        for (int fm = 0; fm < 2; ++fm)
          acc[fm][fn] = __builtin_amdgcn_mfma_f32_16x16x32_bf16(a[fm], b, acc[fm][fn], 0, 0, 0);
      }
    }
    // store (64-B coalesced segments per 16 lanes)
#pragma unroll
    for (int fm = 0; fm < 2; ++fm)
#pragma unroll
      for (int fn = 0; fn < 4; ++fn) {
        const int n = n0 + wn * 64 + fn * 16 + r16;
        if (n < NEMB) {
#pragma unroll
          for (int j = 0; j < 4; ++j) {
            const int m = mc * 128 + wm * 32 + fm * 16 + g * 4 + j;
            out[(size_t)m * NEMB + n] = acc[fm][fn][j] + bias_v[fn];
          }
        }
      }
  }
}

extern "C" void kernel_launch(void* const* d_in, const int* in_sizes, int n_in,
                              void* d_out, int out_size, void* d_ws, size_t ws_size,
                              hipStream_t stream) {
  (void)in_sizes; (void)n_in; (void)out_size; (void)ws_size;
  const float* rin     = (const float*)d_in[0];
  const int*   act     = (const int*)d_in[1];
  const float* en_emb  = (const float*)d_in[2];
  const float* en_bias = (const float*)d_in[3];
  const float* enc_W   = (const float*)d_in[4];
  const float* enc_b   = (const float*)d_in[5];
  const float* dec_W   = (const float*)d_in[6];
  const float* dec_b   = (const float*)d_in[7];
  const float* de_emb  = (const float*)d_in[8];
  const float* de_bias = (const float*)d_in[9];
  float* out = (float*)d_out;

  // workspace layout (floats): part[25*512*256] | z1[512*256] | z2[512*512] | z3b(u16 512*256)
  float* ws   = (float*)d_ws;
  float* part = ws;
  float* z1   = part + (size_t)SPLITS * (B_ * EMBD);
  float* z2   = z1 + (size_t)B_ * EMBD;
  unsigned short* z3b = (unsigned short*)(z2 + (size_t)B_ * HIDD);

  k1_gather_gemm<<<dim3(8, 4, SPLITS), 256, 0, stream>>>(rin, act, en_emb, part);
  k1_reduce<<<dim3((B_ * EMBD) / 256), 256, 0, stream>>>(part, en_bias, z1);
  mlp_gemm<EMBD, EMBD, EMBD, false><<<dim3(8, 8), 256, 0, stream>>>(z1, enc_W, enc_b, z2, nullptr, HIDD);
  mlp_gemm<HIDD, HIDD, HIDD, true><<<dim3(8, 4), 256, 0, stream>>>(z2, dec_W, dec_b, nullptr, z3b, EMBD);
  k4_decode<<<dim3((NEMB + 127) / 128), 512, 0, stream>>>(z3b, de_emb, de_bias, out);
}

// Round 2
// 408.342 us; speedup vs baseline: 1.1366x; 1.1366x over previous
//
#include <hip/hip_runtime.h>

#define B_    512
#define KD    20000
#define EMBD  256
#define HIDD  512
#define NEMB  200000
#define SPLITS 25
#define KSPAN  800   // 20000 / 25, = 25 k-steps of 32
#define TILE_N 64    // k4 de_emb rows per block (200000 % 64 == 0 -> 3125 blocks)

typedef __attribute__((ext_vector_type(8))) short bf16x8;
typedef __attribute__((ext_vector_type(4))) float f32x4;
typedef __attribute__((ext_vector_type(8))) unsigned short u16x8;

__device__ __forceinline__ unsigned short f2bf(float f) {
  unsigned int u = __float_as_uint(f);
  return (unsigned short)((u + 0x7fffu + ((u >> 16) & 1u)) >> 16);  // RNE
}

__device__ __forceinline__ float selu_f(float x) {
  const float kScale = 1.0507009873554805f;
  const float kSA    = 1.7580993408473766f;  // scale*alpha
  return x > 0.0f ? kScale * x : kSA * (__expf(x) - 1.0f);
}

// load 8 consecutive f32 and pack to bf16x8 (16B-aligned source)
__device__ __forceinline__ bf16x8 load8f(const float* __restrict__ p) {
  float4 a = *(const float4*)p;
  float4 b = *(const float4*)(p + 4);
  bf16x8 r;
  r[0] = (short)f2bf(a.x); r[1] = (short)f2bf(a.y);
  r[2] = (short)f2bf(a.z); r[3] = (short)f2bf(a.w);
  r[4] = (short)f2bf(b.x); r[5] = (short)f2bf(b.y);
  r[6] = (short)f2bf(b.z); r[7] = (short)f2bf(b.w);
  return r;
}

__device__ __forceinline__ f32x4 ntload4(const float* __restrict__ p) {
  return __builtin_nontemporal_load((const f32x4*)p);
}

// ---------------- K1: split-K gather GEMM: part[kz] += rin @ en_emb[act] ----
// grid (8,4,25), block 256 (4 waves, 2x2), tile 64x64 per block
__global__ void k1_gather_gemm(const float* __restrict__ rin,
                               const int* __restrict__ act,
                               const float* __restrict__ en_emb,
                               float* __restrict__ part) {
  const int tid = threadIdx.x;
  const int lane = tid & 63, wave = tid >> 6;
  const int wm = wave >> 1, wn = wave & 1;
  const int g = lane >> 4, r16 = lane & 15;
  const int m0 = blockIdx.x * 64 + wm * 32;
  const int n0 = blockIdx.y * 64 + wn * 32;
  const int kz = blockIdx.z;
  // active_dims may be int64 (reference casts to int64): odd words all-zero
  const int is64 = ((act[1] | act[3] | act[5] | act[7]) == 0) ? 1 : 0;

  const f32x4 z4 = {0.f, 0.f, 0.f, 0.f};
  f32x4 acc[2][2];
#pragma unroll
  for (int a = 0; a < 2; ++a)
#pragma unroll
    for (int b = 0; b < 2; ++b) acc[a][b] = z4;

  for (int s = 0; s < 25; ++s) {
    const int k = kz * KSPAN + s * 32;
    const int kb = k + g * 8;
    bf16x8 afr[2];
#pragma unroll
    for (int fm = 0; fm < 2; ++fm) {
      const int row = m0 + fm * 16 + r16;
      afr[fm] = load8f(rin + (size_t)row * KD + kb);
    }
    int idx8[8];
#pragma unroll
    for (int j = 0; j < 8; ++j)
      idx8[j] = is64 ? act[(size_t)(kb + j) * 2] : act[kb + j];
    bf16x8 bfr[2];
#pragma unroll
    for (int fn = 0; fn < 2; ++fn) {
      const int e = n0 + fn * 16 + r16;
#pragma unroll
      for (int j = 0; j < 8; ++j)
        bfr[fn][j] = (short)f2bf(en_emb[(size_t)idx8[j] * EMBD + e]);
    }
#pragma unroll
    for (int fm = 0; fm < 2; ++fm)
#pragma unroll
      for (int fn = 0; fn < 2; ++fn)
        acc[fm][fn] = __builtin_amdgcn_mfma_f32_16x16x32_bf16(afr[fm], bfr[fn], acc[fm][fn], 0, 0, 0);
  }
  float* pz = part + (size_t)kz * (B_ * EMBD);
#pragma unroll
  for (int fm = 0; fm < 2; ++fm)
#pragma unroll
    for (int fn = 0; fn < 2; ++fn) {
      const int n = n0 + fn * 16 + r16;
#pragma unroll
      for (int j = 0; j < 4; ++j) {
        const int m = m0 + fm * 16 + g * 4 + j;  // C/D: row=(l>>4)*4+reg, col=l&15
        pz[(size_t)m * EMBD + n] = acc[fm][fn][j];
      }
    }
}

// ---------------- K1b: reduce splits + bias + selu -> z1 (f32) --------------
__global__ void k1_reduce(const float* __restrict__ part,
                          const float* __restrict__ en_bias,
                          float* __restrict__ z1) {
  const int i = blockIdx.x * blockDim.x + threadIdx.x;  // 0..131071
  float s = 0.f;
#pragma unroll
  for (int p = 0; p < SPLITS; ++p) s += part[(size_t)p * (B_ * EMBD) + i];
  z1[i] = selu_f(s + en_bias[i & (EMBD - 1)]);
}

// ---------------- K2/K3: small MLP GEMM (C = A @ Bw^T), register-only -------
// block 256 (2x2 waves), tile 64x64; A [M][KDIM] lda=LDA, Bw [N][KDIM] ldb=LDB
template <int KDIM, int LDA, int LDB, bool BF16OUT>
__global__ void mlp_gemm(const float* __restrict__ A,
                         const float* __restrict__ Bw,
                         const float* __restrict__ bias,
                         float* __restrict__ outF,
                         unsigned short* __restrict__ outB,
                         int ldo) {
  const int tid = threadIdx.x;
  const int lane = tid & 63, wave = tid >> 6;
  const int wm = wave >> 1, wn = wave & 1;
  const int g = lane >> 4, r16 = lane & 15;
  const int m0 = blockIdx.x * 64 + wm * 32;
  const int n0 = blockIdx.y * 64 + wn * 32;

  const f32x4 z4 = {0.f, 0.f, 0.f, 0.f};
  f32x4 acc[2][2];
#pragma unroll
  for (int a = 0; a < 2; ++a)
#pragma unroll
    for (int b = 0; b < 2; ++b) acc[a][b] = z4;

#pragma unroll
  for (int k = 0; k < KDIM; k += 32) {
    const int kb = k + g * 8;
    bf16x8 afr[2], bfr[2];
#pragma unroll
    for (int fm = 0; fm < 2; ++fm)
      afr[fm] = load8f(A + (size_t)(m0 + fm * 16 + r16) * LDA + kb);
#pragma unroll
    for (int fn = 0; fn < 2; ++fn)
      bfr[fn] = load8f(Bw + (size_t)(n0 + fn * 16 + r16) * LDB + kb);
#pragma unroll
    for (int fm = 0; fm < 2; ++fm)
#pragma unroll
      for (int fn = 0; fn < 2; ++fn)
        acc[fm][fn] = __builtin_amdgcn_mfma_f32_16x16x32_bf16(afr[fm], bfr[fn], acc[fm][fn], 0, 0, 0);
  }
#pragma unroll
  for (int fm = 0; fm < 2; ++fm)
#pragma unroll
    for (int fn = 0; fn < 2; ++fn) {
      const int n = n0 + fn * 16 + r16;
      const float bv = bias[n];
#pragma unroll
      for (int j = 0; j < 4; ++j) {
        const int m = m0 + fm * 16 + g * 4 + j;
        const float v = selu_f(acc[fm][fn][j] + bv);
        if constexpr (BF16OUT)
          outB[(size_t)m * ldo + n] = f2bf(v);
        else
          outF[(size_t)m * ldo + n] = v;
      }
    }
}

// ---------------- K4: out = z3b @ de_emb^T + de_bias ------------------------
// block 512 (8 waves, 4Mx2N), per block: TILE_N n-rows staged in LDS (bf16,
// XOR-swizzled, 32 KB -> 4 blocks/CU), loop 4 m-chunks of 128; A-frags from
// L2-resident z3b; nt stores (no RFO) + nt loads for streaming de_emb.
__global__ void k4_decode(const unsigned short* __restrict__ z3b,  // [512][256] bf16
                          const float* __restrict__ de_emb,        // [NEMB][256]
                          const float* __restrict__ de_bias,       // [NEMB]
                          float* __restrict__ out) {               // [512][NEMB]
  __shared__ unsigned short Bs[TILE_N * 256];  // 32 KB

  // bijective XCD-aware swizzle (nwg % 8 != 0 safe)
  const int nwg = gridDim.x;
  int bid = blockIdx.x;
  const int q = nwg >> 3, r = nwg & 7;
  const int xcd = bid & 7, sub = bid >> 3;
  const int wg = (xcd < r ? xcd * (q + 1) : r * (q + 1) + (xcd - r) * q) + sub;
  const int n0 = wg * TILE_N;

  const int tid = threadIdx.x;
  // ---- stage de_emb tile -> Bs (bf16, swizzled) ----
  {
    const int sr = tid >> 3, sq = tid & 7;  // row 0..63, k-octile 0..7
    const float* src = de_emb + (size_t)(n0 + sr) * EMBD;
#pragma unroll
    for (int i = 0; i < 4; ++i) {
      const int k0 = sq * 32 + i * 8;
      f32x4 x = ntload4(src + k0);
      f32x4 y = ntload4(src + k0 + 4);
      u16x8 v;
      v[0] = f2bf(x[0]); v[1] = f2bf(x[1]); v[2] = f2bf(x[2]); v[3] = f2bf(x[3]);
      v[4] = f2bf(y[0]); v[5] = f2bf(y[1]); v[6] = f2bf(y[2]); v[7] = f2bf(y[3]);
      const int sidx = sr * 256 + (k0 ^ ((sr & 7) << 3));
      *(u16x8*)(&Bs[sidx]) = v;
    }
  }
  __syncthreads();

  const int lane = tid & 63, wave = tid >> 6;  // 8 waves
  const int wm = wave >> 1, wn = wave & 1;     // 4(M) x 2(N)
  const int g = lane >> 4, r16 = lane & 15;

  float bias_v[2];
#pragma unroll
  for (int fn = 0; fn < 2; ++fn)
    bias_v[fn] = de_bias[n0 + wn * 32 + fn * 16 + r16];

  const f32x4 z4 = {0.f, 0.f, 0.f, 0.f};
  for (int mc = 0; mc < 4; ++mc) {
    f32x4 acc[2][2];
#pragma unroll
    for (int a = 0; a < 2; ++a)
#pragma unroll
      for (int b = 0; b < 2; ++b) acc[a][b] = z4;

#pragma unroll
    for (int kk = 0; kk < 8; ++kk) {
      bf16x8 a[2];
#pragma unroll
      for (int fm = 0; fm < 2; ++fm) {
        const int m = mc * 128 + wm * 32 + fm * 16 + r16;
        a[fm] = *(const bf16x8*)(z3b + (size_t)m * EMBD + kk * 32 + g * 8);
      }
#pragma unroll
      for (int fn = 0; fn < 2; ++fn) {
        const int rr = wn * 32 + fn * 16 + r16;
        const int koff = (kk * 32 + g * 8) ^ ((rr & 7) << 3);
        const bf16x8 b = *(const bf16x8*)(&Bs[rr * 256 + koff]);
#pragma unroll
        for (int fm = 0; fm < 2; ++fm)
          acc[fm][fn] = __builtin_amdgcn_mfma_f32_16x16x32_bf16(a[fm], b, acc[fm][fn], 0, 0, 0);
      }
    }
    // nt stores: no L2 allocate -> no RFO fetch of output lines
#pragma unroll
    for (int fm = 0; fm < 2; ++fm)
#pragma unroll
      for (int fn = 0; fn < 2; ++fn) {
        const int n = n0 + wn * 32 + fn * 16 + r16;
#pragma unroll
        for (int j = 0; j < 4; ++j) {
          const int m = mc * 128 + wm * 32 + fm * 16 + g * 4 + j;
          __builtin_nontemporal_store(acc[fm][fn][j] + bias_v[fn],
                                      out + (size_t)m * NEMB + n);
        }
      }
  }
}

extern "C" void kernel_launch(void* const* d_in, const int* in_sizes, int n_in,
                              void* d_out, int out_size, void* d_ws, size_t ws_size,
                              hipStream_t stream) {
  (void)in_sizes; (void)n_in; (void)out_size; (void)ws_size;
  const float* rin     = (const float*)d_in[0];
  const int*   act     = (const int*)d_in[1];
  const float* en_emb  = (const float*)d_in[2];
  const float* en_bias = (const float*)d_in[3];
  const float* enc_W   = (const float*)d_in[4];
  const float* enc_b   = (const float*)d_in[5];
  const float* dec_W   = (const float*)d_in[6];
  const float* dec_b   = (const float*)d_in[7];
  const float* de_emb  = (const float*)d_in[8];
  const float* de_bias = (const float*)d_in[9];
  float* out = (float*)d_out;

  // workspace layout (floats): part[25*512*256] | z1[512*256] | z2[512*512] | z3b(u16 512*256)
  float* ws   = (float*)d_ws;
  float* part = ws;
  float* z1   = part + (size_t)SPLITS * (B_ * EMBD);
  float* z2   = z1 + (size_t)B_ * EMBD;
  unsigned short* z3b = (unsigned short*)(z2 + (size_t)B_ * HIDD);

  k1_gather_gemm<<<dim3(8, 4, SPLITS), 256, 0, stream>>>(rin, act, en_emb, part);
  k1_reduce<<<dim3((B_ * EMBD) / 256), 256, 0, stream>>>(part, en_bias, z1);
  mlp_gemm<EMBD, EMBD, EMBD, false><<<dim3(8, 8), 256, 0, stream>>>(z1, enc_W, enc_b, z2, nullptr, HIDD);
  mlp_gemm<HIDD, HIDD, HIDD, true><<<dim3(8, 4), 256, 0, stream>>>(z2, dec_W, dec_b, nullptr, z3b, EMBD);
  k4_decode<<<dim3(NEMB / TILE_N), 512, 0, stream>>>(z3b, de_emb, de_bias, out);
}